// Round 1
// baseline (1791.341 us; speedup 1.0000x reference)
//
#include <hip/hip_runtime.h>
#include <hip/hip_bf16.h>

// Problem dims
#define BB 64
#define TT 168
#define NN 64
#define FF 17
#define HID 128
#define GATES 512   // 4*HID
#define NLAYERS 4
#define NROWS (BB*TT)   // 10752

// Workspace layout (float offsets)
#define WS_W1SRC 0
#define WS_W1DST 32
#define WS_W2SRC 64
#define WS_W2DST 192
#define WS_BSUM  320                    // 4*512
#define WS_W2T   2560                   // 128*128
#define WS_SEQ   19456                  // NROWS*HID = 1376256
#define WS_XG    1395712                // NROWS*512 = 5505024
#define WS_HSEQ0 6900736                // 4 buffers of NROWS*HID
#define HSEQ_SZ  1376256
// total = 6900736 + 4*1376256 = 12405760 floats = 49.6 MB

// ---------------- K0: small precompute ----------------
__global__ void prep_kernel(const float* __restrict__ W1, const float* __restrict__ a1,
                            const float* __restrict__ W2, const float* __restrict__ a2,
                            const float* __restrict__ bih, const float* __restrict__ bhh,
                            float* __restrict__ ws) {
    int tid = threadIdx.x;
    // w1src/w1dst: [17] each
    if (tid < 34) {
        int f = tid % FF, half = tid / FF;
        float acc = 0.f;
        for (int o = 0; o < HID; o++) acc += W1[f*HID + o] * a1[half*HID + o];
        ws[(half ? WS_W1DST : WS_W1SRC) + f] = acc;
    }
    // w2src/w2dst: [128] each
    {
        int k = tid & 127, half = tid >> 7;   // tid<256 covers both halves
        float acc = 0.f;
        for (int o = 0; o < HID; o++) acc += W2[k*HID + o] * a2[half*HID + o];
        ws[(half ? WS_W2DST : WS_W2SRC) + k] = acc;
    }
    // bsum = bih + bhh (4*512)
    for (int idx = tid; idx < NLAYERS*GATES; idx += 256) ws[WS_BSUM + idx] = bih[idx] + bhh[idx];
    // W2T[o][k] = W2[k][o]
    for (int idx = tid; idx < HID*HID; idx += 256) {
        int k = idx >> 7, o = idx & 127;
        ws[WS_W2T + o*HID + k] = W2[idx];
    }
}

// ---------------- K1: fused GAT1 + GAT2(site row) ----------------
struct __align__(16) GatSmem {
    float attn_h1[64*132];   // P2-P3: attn rows (stride 68); P4-P7: h1 rows (stride 132)
    float xsT[FF*64];        // [f][n]
    float xbarT[FF*64];      // [f][i]
    float W1s[FF*HID];
    float src1[64];
    float dst1[64];
    float rinv[64];
    float dst2[64];
    float att2[64];
    float hbar[HID];
    float misc[8];
    unsigned long long adjbits[64];
};

__global__ __launch_bounds__(256) void gat_fused(const float* __restrict__ x, const int* __restrict__ adj,
                                                 const float* __restrict__ W1, const float* __restrict__ ws,
                                                 float* __restrict__ seq, const int* __restrict__ site_ptr) {
    __shared__ GatSmem sm;
    const int tid = threadIdx.x;
    const int tt = blockIdx.x, bb = blockIdx.y;
    const float* xblk = x + ((size_t)(bb*TT + tt)) * (NN*FF);

    // P0: load x transposed, W1, adj bitmasks
    for (int idx = tid; idx < NN*FF; idx += 256) {
        int n = idx / FF, f = idx % FF;
        sm.xsT[f*64 + n] = xblk[idx];
    }
    for (int idx = tid; idx < FF*HID; idx += 256) sm.W1s[idx] = W1[idx];
    {
        int w = tid >> 6, lane = tid & 63;
        for (int r = w*16; r < w*16 + 16; r++) {
            int val = adj[r*64 + lane];
            unsigned long long m = __ballot(val > 0);
            if (lane == 0) sm.adjbits[r] = m | (1ull << r);
        }
    }
    __syncthreads();

    // P1: src1/dst1 = x . (W1 @ a1-halves)
    if (tid < 128) {
        int n = tid & 63, half = tid >> 6;
        const float* wv = ws + (half ? WS_W1DST : WS_W1SRC);
        float acc = 0.f;
        #pragma unroll
        for (int f = 0; f < FF; f++) acc += sm.xsT[f*64 + n] * wv[f];
        if (half) sm.dst1[n] = acc; else sm.src1[n] = acc;
    }
    __syncthreads();

    // P2: attention rows -> unnormalized p into attn (stride 68), rinv
    {
        int q = tid & 3, i = tid >> 2;
        unsigned long long ab = sm.adjbits[i];
        float si = sm.src1[i];
        float v[16];
        float vmax = -1e30f;
        #pragma unroll
        for (int u = 0; u < 16; u++) {
            int jj = q*16 + u;
            float e = si + sm.dst1[jj];
            float lv = fmaxf(e, 0.2f*e);            // leaky_relu(0.2)
            lv = ((ab >> jj) & 1ull) ? lv : -1e9f;  // mask
            v[u] = lv;
            vmax = fmaxf(vmax, lv);
        }
        vmax = fmaxf(vmax, __shfl_xor(vmax, 1, 4));
        vmax = fmaxf(vmax, __shfl_xor(vmax, 2, 4));
        float s = 0.f;
        float* arow = &sm.attn_h1[i*68];
        #pragma unroll
        for (int u = 0; u < 16; u++) {
            float p = __expf(v[u] - vmax);
            s += p;
            arow[q*16 + u] = p;
        }
        s += __shfl_xor(s, 1, 4);
        s += __shfl_xor(s, 2, 4);
        if (q == 0) sm.rinv[i] = 1.f / s;
    }
    __syncthreads();

    // P3: xbarT[f][i] = (P @ X)[i][f] / rowsum
    {
        int i = tid & 63, q = tid >> 6;
        const float* arow = &sm.attn_h1[i*68];
        float acc[5] = {0.f,0.f,0.f,0.f,0.f};
        const int nf = (q == 0) ? 5 : 4;
        for (int j4 = 0; j4 < 16; j4++) {
            float4 a4 = *(const float4*)(arow + j4*4);
            #pragma unroll
            for (int u = 0; u < 5; u++) {
                if (u < nf) {
                    int f = q + 4*u;
                    float4 x4 = *(const float4*)(&sm.xsT[f*64 + j4*4]);
                    acc[u] += a4.x*x4.x + a4.y*x4.y + a4.z*x4.z + a4.w*x4.w;
                }
            }
        }
        float ri = sm.rinv[i];
        #pragma unroll
        for (int u = 0; u < 5; u++) {
            if (u < nf) sm.xbarT[(q + 4*u)*64 + i] = acc[u] * ri;
        }
    }
    __syncthreads();

    // P4: h1[i][o] (stride 132) = xbar @ W1   (overwrites attn region)
    {
        int og = tid & 15, ig = tid >> 4;   // o=8*og, i=4*ig
        float acc[4][8];
        #pragma unroll
        for (int u = 0; u < 4; u++)
            #pragma unroll
            for (int v = 0; v < 8; v++) acc[u][v] = 0.f;
        for (int f = 0; f < FF; f++) {
            float4 xb = *(const float4*)(&sm.xbarT[f*64 + ig*4]);
            float4 wa = *(const float4*)(&sm.W1s[f*HID + og*8]);
            float4 wb = *(const float4*)(&sm.W1s[f*HID + og*8 + 4]);
            float xv[4] = {xb.x, xb.y, xb.z, xb.w};
            float wv[8] = {wa.x, wa.y, wa.z, wa.w, wb.x, wb.y, wb.z, wb.w};
            #pragma unroll
            for (int u = 0; u < 4; u++)
                #pragma unroll
                for (int v = 0; v < 8; v++) acc[u][v] += xv[u] * wv[v];
        }
        #pragma unroll
        for (int u = 0; u < 4; u++) {
            float4 o0 = {acc[u][0], acc[u][1], acc[u][2], acc[u][3]};
            float4 o1 = {acc[u][4], acc[u][5], acc[u][6], acc[u][7]};
            *(float4*)(&sm.attn_h1[(ig*4+u)*132 + og*8]) = o0;
            *(float4*)(&sm.attn_h1[(ig*4+u)*132 + og*8 + 4]) = o1;
        }
    }
    __syncthreads();

    // P5: dst2[j] = h1[j].w2dst ; src2 = h1[site].w2src
    const int site = site_ptr[0];
    if (tid < 64) {
        int jj = tid;
        const float4* hr = (const float4*)(&sm.attn_h1[jj*132]);
        const float4* wd = (const float4*)(ws + WS_W2DST);
        float acc = 0.f;
        #pragma unroll
        for (int k = 0; k < 32; k++) {
            float4 h4 = hr[k], w4 = wd[k];
            acc += h4.x*w4.x + h4.y*w4.y + h4.z*w4.z + h4.w*w4.w;
        }
        sm.dst2[jj] = acc;
    } else if (tid < 128) {
        int l = tid - 64;
        float2 h2 = *(const float2*)(&sm.attn_h1[site*132 + l*2]);
        float2 w2 = *(const float2*)(ws + WS_W2SRC + l*2);
        float p = h2.x*w2.x + h2.y*w2.y;
        #pragma unroll
        for (int d = 1; d < 64; d <<= 1) p += __shfl_xor(p, d);
        if (l == 0) sm.misc[0] = p;
    }
    __syncthreads();

    // P5b: attn2 over site row
    if (tid < 64) {
        int jj = tid;
        unsigned long long ab = sm.adjbits[site];
        float e = sm.misc[0] + sm.dst2[jj];
        float lv = fmaxf(e, 0.2f*e);
        lv = ((ab >> jj) & 1ull) ? lv : -1e9f;
        float m = lv;
        #pragma unroll
        for (int d = 1; d < 64; d <<= 1) m = fmaxf(m, __shfl_xor(m, d));
        float p = __expf(lv - m);
        float s = p;
        #pragma unroll
        for (int d = 1; d < 64; d <<= 1) s += __shfl_xor(s, d);
        sm.att2[jj] = p / s;
    }
    __syncthreads();

    // P6: hbar[k] = sum_j att2[j] * h1[j][k]
    if (tid < 128) {
        int k = tid;
        float acc = 0.f;
        for (int jj = 0; jj < 64; jj++) acc += sm.att2[jj] * sm.attn_h1[jj*132 + k];
        sm.hbar[k] = acc;
    }
    __syncthreads();

    // P7: seq[b][t][o] = hbar @ W2   (via W2T rows, global)
    if (tid < 128) {
        int o = tid;
        const float4* w2t = (const float4*)(ws + WS_W2T + o*HID);
        const float4* hb4 = (const float4*)sm.hbar;
        float acc = 0.f;
        #pragma unroll
        for (int k4 = 0; k4 < 32; k4++) {
            float4 h4 = hb4[k4], w4 = w2t[k4];
            acc += h4.x*w4.x + h4.y*w4.y + h4.z*w4.z + h4.w*w4.w;
        }
        seq[((size_t)(bb*TT + tt))*HID + o] = acc;
    }
}

// ---------------- K2: input GEMM  Xg[r][j] = seq[r] . Wih[j] + bsum[j] ----------------
__global__ __launch_bounds__(512) void lstm_ingemm(const float* __restrict__ in_seq,
                                                   const float* __restrict__ Wih_l,
                                                   const float* __restrict__ bsum_l,
                                                   float* __restrict__ Xg) {
    const int j = threadIdx.x;
    const float2* wr = (const float2*)(Wih_l + j*HID);
    float2 w[64];
    #pragma unroll
    for (int k = 0; k < 64; k++) w[k] = wr[k];
    const float bj = bsum_l[j];
    const int r0 = blockIdx.x * (NROWS/256);   // 42 rows each
    for (int rr = 0; rr < NROWS/256; rr++) {
        int r = r0 + rr;
        const float2* xr = (const float2*)(in_seq + (size_t)r*HID);
        float ax = 0.f, ay = 0.f;
        #pragma unroll
        for (int k = 0; k < 64; k++) {
            float2 xv = xr[k];
            ax += w[k].x * xv.x;
            ay += w[k].y * xv.y;
        }
        Xg[(size_t)r*GATES + j] = bj + ax + ay;
    }
}

// ---------------- K3: recurrence, one block per batch element ----------------
__global__ __launch_bounds__(512) void lstm_rec(const float* __restrict__ Xg,
                                                const float* __restrict__ Whh_l,
                                                float* __restrict__ hseq_l) {
    const int b = blockIdx.x;
    const int j = threadIdx.x;
    __shared__ __align__(16) float h_s[HID];
    __shared__ float g_s[GATES];
    const float4* wr = (const float4*)(Whh_l + j*HID);
    float4 w[32];
    #pragma unroll
    for (int k = 0; k < 32; k++) w[k] = wr[k];
    float c = 0.f;
    if (j < HID) h_s[j] = 0.f;
    __syncthreads();
    const float* xg_b = Xg + (size_t)b*TT*GATES;
    float* hout_b = hseq_l + (size_t)b*TT*HID;
    for (int t = 0; t < TT; t++) {
        float acc = xg_b[t*GATES + j];
        const float4* h4 = (const float4*)h_s;
        #pragma unroll
        for (int k = 0; k < 32; k++) {
            float4 hv = h4[k];
            acc += w[k].x*hv.x + w[k].y*hv.y + w[k].z*hv.z + w[k].w*hv.w;
        }
        g_s[j] = acc;
        __syncthreads();
        if (j < HID) {
            float gi = g_s[j], gf = g_s[j+128], gg = g_s[j+256], go = g_s[j+384];
            float si = 1.f/(1.f + __expf(-gi));
            float sf = 1.f/(1.f + __expf(-gf));
            float so = 1.f/(1.f + __expf(-go));
            float tg = tanhf(gg);
            c = sf*c + si*tg;
            float h = so*tanhf(c);
            h_s[j] = h;
            hout_b[t*HID + j] = h;
        }
        __syncthreads();
    }
}

// ---------------- K4: final linear ----------------
__global__ void final_lin(const float* __restrict__ ws, const float* __restrict__ Wlin,
                          const float* __restrict__ blin, float* __restrict__ out) {
    const int b = blockIdx.x, l = threadIdx.x;  // 64 threads
    float acc = 0.f;
    #pragma unroll
    for (int u = 0; u < 8; u++) {
        int idx = u*64 + l;
        int layer = idx >> 7, k = idx & 127;
        const float* hs = ws + WS_HSEQ0 + (size_t)layer*HSEQ_SZ;
        acc += hs[((size_t)b*TT + (TT-1))*HID + k] * Wlin[idx];
    }
    #pragma unroll
    for (int d = 1; d < 64; d <<= 1) acc += __shfl_xor(acc, d);
    if (l == 0) out[b] = acc + blin[0];
}

extern "C" void kernel_launch(void* const* d_in, const int* in_sizes, int n_in,
                              void* d_out, int out_size, void* d_ws, size_t ws_size,
                              hipStream_t stream) {
    const float* x    = (const float*)d_in[0];
    const int*   adj  = (const int*)d_in[1];
    const float* W1   = (const float*)d_in[2];
    const float* a1   = (const float*)d_in[3];
    const float* W2   = (const float*)d_in[4];
    const float* a2   = (const float*)d_in[5];
    const float* Wih  = (const float*)d_in[6];
    const float* Whh  = (const float*)d_in[7];
    const float* bih  = (const float*)d_in[8];
    const float* bhh  = (const float*)d_in[9];
    const float* Wlin = (const float*)d_in[10];
    const float* blin = (const float*)d_in[11];
    const int*   site = (const int*)d_in[12];
    float* ws  = (float*)d_ws;
    float* out = (float*)d_out;

    prep_kernel<<<1, 256, 0, stream>>>(W1, a1, W2, a2, bih, bhh, ws);
    gat_fused<<<dim3(TT, BB), 256, 0, stream>>>(x, adj, W1, ws, ws + WS_SEQ, site);
    for (int l = 0; l < NLAYERS; l++) {
        const float* in_seq = (l == 0) ? (ws + WS_SEQ) : (ws + WS_HSEQ0 + (size_t)(l-1)*HSEQ_SZ);
        lstm_ingemm<<<256, 512, 0, stream>>>(in_seq, Wih + (size_t)l*GATES*HID,
                                             ws + WS_BSUM + l*GATES, ws + WS_XG);
        lstm_rec<<<64, 512, 0, stream>>>(ws + WS_XG, Whh + (size_t)l*GATES*HID,
                                         ws + WS_HSEQ0 + (size_t)l*HSEQ_SZ);
    }
    final_lin<<<64, 64, 0, stream>>>(ws, Wlin, blin, out);
}

// Round 2
// 1554.996 us; speedup vs baseline: 1.1520x; 1.1520x over previous
//
#include <hip/hip_runtime.h>
#include <hip/hip_bf16.h>

// Problem dims
#define BB 64
#define TT 168
#define NN 64
#define FF 17
#define HID 128
#define GATES 512   // 4*HID
#define NLAYERS 4
#define NROWS (BB*TT)   // 10752

// Workspace layout (float offsets)
#define WS_W1SRC 0
#define WS_W1DST 32
#define WS_W2SRC 64
#define WS_W2DST 192
#define WS_BSUM  320                    // 4*512
#define WS_W2T   2560                   // 128*128
#define WS_SEQ   19456                  // NROWS*HID = 1376256
#define WS_XG    1395712                // NROWS*512 = 5505024
#define WS_HSEQ0 6900736                // 4 buffers of NROWS*HID
#define HSEQ_SZ  1376256
// total = 6900736 + 4*1376256 = 12405760 floats = 49.6 MB

// ---------------- K0: small precompute ----------------
__global__ void prep_kernel(const float* __restrict__ W1, const float* __restrict__ a1,
                            const float* __restrict__ W2, const float* __restrict__ a2,
                            const float* __restrict__ bih, const float* __restrict__ bhh,
                            float* __restrict__ ws) {
    int tid = threadIdx.x;
    // w1src/w1dst: [17] each
    if (tid < 34) {
        int f = tid % FF, half = tid / FF;
        float acc = 0.f;
        for (int o = 0; o < HID; o++) acc += W1[f*HID + o] * a1[half*HID + o];
        ws[(half ? WS_W1DST : WS_W1SRC) + f] = acc;
    }
    // w2src/w2dst: [128] each
    {
        int k = tid & 127, half = tid >> 7;   // tid<256 covers both halves
        float acc = 0.f;
        for (int o = 0; o < HID; o++) acc += W2[k*HID + o] * a2[half*HID + o];
        ws[(half ? WS_W2DST : WS_W2SRC) + k] = acc;
    }
    // bsum = bih + bhh (4*512)
    for (int idx = tid; idx < NLAYERS*GATES; idx += 256) ws[WS_BSUM + idx] = bih[idx] + bhh[idx];
    // W2T[o][k] = W2[k][o]
    for (int idx = tid; idx < HID*HID; idx += 256) {
        int k = idx >> 7, o = idx & 127;
        ws[WS_W2T + o*HID + k] = W2[idx];
    }
}

// ---------------- K1: fused GAT1 + GAT2(site row) ----------------
struct __align__(16) GatSmem {
    float attn_h1[64*132];   // P2-P3: attn rows (stride 68); P4-P7: h1 rows (stride 132)
    float xsT[FF*64];        // [f][n]
    float xbarT[FF*64];      // [f][i]
    float W1s[FF*HID];
    float src1[64];
    float dst1[64];
    float rinv[64];
    float dst2[64];
    float att2[64];
    float hbar[HID];
    float misc[8];
    unsigned long long adjbits[64];
};

__global__ __launch_bounds__(256) void gat_fused(const float* __restrict__ x, const int* __restrict__ adj,
                                                 const float* __restrict__ W1, const float* __restrict__ ws,
                                                 float* __restrict__ seq, const int* __restrict__ site_ptr) {
    __shared__ GatSmem sm;
    const int tid = threadIdx.x;
    const int tt = blockIdx.x, bb = blockIdx.y;
    const float* xblk = x + ((size_t)(bb*TT + tt)) * (NN*FF);

    // P0: load x transposed, W1, adj bitmasks
    for (int idx = tid; idx < NN*FF; idx += 256) {
        int n = idx / FF, f = idx % FF;
        sm.xsT[f*64 + n] = xblk[idx];
    }
    for (int idx = tid; idx < FF*HID; idx += 256) sm.W1s[idx] = W1[idx];
    {
        int w = tid >> 6, lane = tid & 63;
        for (int r = w*16; r < w*16 + 16; r++) {
            int val = adj[r*64 + lane];
            unsigned long long m = __ballot(val > 0);
            if (lane == 0) sm.adjbits[r] = m | (1ull << r);
        }
    }
    __syncthreads();

    // P1: src1/dst1 = x . (W1 @ a1-halves)
    if (tid < 128) {
        int n = tid & 63, half = tid >> 6;
        const float* wv = ws + (half ? WS_W1DST : WS_W1SRC);
        float acc = 0.f;
        #pragma unroll
        for (int f = 0; f < FF; f++) acc += sm.xsT[f*64 + n] * wv[f];
        if (half) sm.dst1[n] = acc; else sm.src1[n] = acc;
    }
    __syncthreads();

    // P2: attention rows -> unnormalized p into attn (stride 68), rinv
    {
        int q = tid & 3, i = tid >> 2;
        unsigned long long ab = sm.adjbits[i];
        float si = sm.src1[i];
        float v[16];
        float vmax = -1e30f;
        #pragma unroll
        for (int u = 0; u < 16; u++) {
            int jj = q*16 + u;
            float e = si + sm.dst1[jj];
            float lv = fmaxf(e, 0.2f*e);            // leaky_relu(0.2)
            lv = ((ab >> jj) & 1ull) ? lv : -1e9f;  // mask
            v[u] = lv;
            vmax = fmaxf(vmax, lv);
        }
        vmax = fmaxf(vmax, __shfl_xor(vmax, 1, 4));
        vmax = fmaxf(vmax, __shfl_xor(vmax, 2, 4));
        float s = 0.f;
        float* arow = &sm.attn_h1[i*68];
        #pragma unroll
        for (int u = 0; u < 16; u++) {
            float p = __expf(v[u] - vmax);
            s += p;
            arow[q*16 + u] = p;
        }
        s += __shfl_xor(s, 1, 4);
        s += __shfl_xor(s, 2, 4);
        if (q == 0) sm.rinv[i] = 1.f / s;
    }
    __syncthreads();

    // P3: xbarT[f][i] = (P @ X)[i][f] / rowsum
    {
        int i = tid & 63, q = tid >> 6;
        const float* arow = &sm.attn_h1[i*68];
        float acc[5] = {0.f,0.f,0.f,0.f,0.f};
        const int nf = (q == 0) ? 5 : 4;
        for (int j4 = 0; j4 < 16; j4++) {
            float4 a4 = *(const float4*)(arow + j4*4);
            #pragma unroll
            for (int u = 0; u < 5; u++) {
                if (u < nf) {
                    int f = q + 4*u;
                    float4 x4 = *(const float4*)(&sm.xsT[f*64 + j4*4]);
                    acc[u] += a4.x*x4.x + a4.y*x4.y + a4.z*x4.z + a4.w*x4.w;
                }
            }
        }
        float ri = sm.rinv[i];
        #pragma unroll
        for (int u = 0; u < 5; u++) {
            if (u < nf) sm.xbarT[(q + 4*u)*64 + i] = acc[u] * ri;
        }
    }
    __syncthreads();

    // P4: h1[i][o] (stride 132) = xbar @ W1   (overwrites attn region)
    {
        int og = tid & 15, ig = tid >> 4;   // o=8*og, i=4*ig
        float acc[4][8];
        #pragma unroll
        for (int u = 0; u < 4; u++)
            #pragma unroll
            for (int v = 0; v < 8; v++) acc[u][v] = 0.f;
        for (int f = 0; f < FF; f++) {
            float4 xb = *(const float4*)(&sm.xbarT[f*64 + ig*4]);
            float4 wa = *(const float4*)(&sm.W1s[f*HID + og*8]);
            float4 wb = *(const float4*)(&sm.W1s[f*HID + og*8 + 4]);
            float xv[4] = {xb.x, xb.y, xb.z, xb.w};
            float wv[8] = {wa.x, wa.y, wa.z, wa.w, wb.x, wb.y, wb.z, wb.w};
            #pragma unroll
            for (int u = 0; u < 4; u++)
                #pragma unroll
                for (int v = 0; v < 8; v++) acc[u][v] += xv[u] * wv[v];
        }
        #pragma unroll
        for (int u = 0; u < 4; u++) {
            float4 o0 = {acc[u][0], acc[u][1], acc[u][2], acc[u][3]};
            float4 o1 = {acc[u][4], acc[u][5], acc[u][6], acc[u][7]};
            *(float4*)(&sm.attn_h1[(ig*4+u)*132 + og*8]) = o0;
            *(float4*)(&sm.attn_h1[(ig*4+u)*132 + og*8 + 4]) = o1;
        }
    }
    __syncthreads();

    // P5: dst2[j] = h1[j].w2dst ; src2 = h1[site].w2src
    const int site = site_ptr[0];
    if (tid < 64) {
        int jj = tid;
        const float4* hr = (const float4*)(&sm.attn_h1[jj*132]);
        const float4* wd = (const float4*)(ws + WS_W2DST);
        float acc = 0.f;
        #pragma unroll
        for (int k = 0; k < 32; k++) {
            float4 h4 = hr[k], w4 = wd[k];
            acc += h4.x*w4.x + h4.y*w4.y + h4.z*w4.z + h4.w*w4.w;
        }
        sm.dst2[jj] = acc;
    } else if (tid < 128) {
        int l = tid - 64;
        float2 h2 = *(const float2*)(&sm.attn_h1[site*132 + l*2]);
        float2 w2 = *(const float2*)(ws + WS_W2SRC + l*2);
        float p = h2.x*w2.x + h2.y*w2.y;
        #pragma unroll
        for (int d = 1; d < 64; d <<= 1) p += __shfl_xor(p, d);
        if (l == 0) sm.misc[0] = p;
    }
    __syncthreads();

    // P5b: attn2 over site row
    if (tid < 64) {
        int jj = tid;
        unsigned long long ab = sm.adjbits[site];
        float e = sm.misc[0] + sm.dst2[jj];
        float lv = fmaxf(e, 0.2f*e);
        lv = ((ab >> jj) & 1ull) ? lv : -1e9f;
        float m = lv;
        #pragma unroll
        for (int d = 1; d < 64; d <<= 1) m = fmaxf(m, __shfl_xor(m, d));
        float p = __expf(lv - m);
        float s = p;
        #pragma unroll
        for (int d = 1; d < 64; d <<= 1) s += __shfl_xor(s, d);
        sm.att2[jj] = p / s;
    }
    __syncthreads();

    // P6: hbar[k] = sum_j att2[j] * h1[j][k]
    if (tid < 128) {
        int k = tid;
        float acc = 0.f;
        for (int jj = 0; jj < 64; jj++) acc += sm.att2[jj] * sm.attn_h1[jj*132 + k];
        sm.hbar[k] = acc;
    }
    __syncthreads();

    // P7: seq[b][t][o] = hbar @ W2   (via W2T rows, global)
    if (tid < 128) {
        int o = tid;
        const float4* w2t = (const float4*)(ws + WS_W2T + o*HID);
        const float4* hb4 = (const float4*)sm.hbar;
        float acc = 0.f;
        #pragma unroll
        for (int k4 = 0; k4 < 32; k4++) {
            float4 h4 = hb4[k4], w4 = w2t[k4];
            acc += h4.x*w4.x + h4.y*w4.y + h4.z*w4.z + h4.w*w4.w;
        }
        seq[((size_t)(bb*TT + tt))*HID + o] = acc;
    }
}

// ---------------- K2: input GEMM  Xg[r][j] = seq[r] . Wih[j] + bsum[j] ----------------
__global__ __launch_bounds__(512) void lstm_ingemm(const float* __restrict__ in_seq,
                                                   const float* __restrict__ Wih_l,
                                                   const float* __restrict__ bsum_l,
                                                   float* __restrict__ Xg) {
    const int j = threadIdx.x;
    const float4* wr = (const float4*)(Wih_l + j*HID);
    float4 w[32];
    #pragma unroll
    for (int k = 0; k < 32; k++) w[k] = wr[k];
    const float bj = bsum_l[j];
    const int r0 = blockIdx.x * (NROWS/256);   // 42 rows each
    for (int rr = 0; rr < NROWS/256; rr++) {
        int r = r0 + rr;
        const float4* xr = (const float4*)(in_seq + (size_t)r*HID);
        float ax = 0.f, ay = 0.f, az = 0.f, aw = 0.f;
        #pragma unroll
        for (int k = 0; k < 32; k++) {
            float4 xv = xr[k];
            ax += w[k].x * xv.x;
            ay += w[k].y * xv.y;
            az += w[k].z * xv.z;
            aw += w[k].w * xv.w;
        }
        Xg[(size_t)r*GATES + j] = bj + ((ax + ay) + (az + aw));
    }
}

// ---------------- K3: recurrence, one block per batch element ----------------
// Outer-product tiling: thread owns 4 consecutive gates x k-chunk of 32.
// kc = tid>>7 (wave-uniform -> h-chunk reads are LDS broadcasts),
// gg = tid&127 -> gates 4*gg..4*gg+3.
// LDS insts/step: 64 bcast b128 + 8 b128 partial writes + 32 b32 reduce reads (+2 h writes)
// vs 256 b128 in the round-1 version.
__global__ __launch_bounds__(512, 2) void lstm_rec(const float* __restrict__ Xg,
                                                   const float* __restrict__ Whh_l,
                                                   float* __restrict__ hseq_l) {
    const int b = blockIdx.x;
    const int tid = threadIdx.x;
    const int kc = tid >> 7;     // 0..3, uniform within wave
    const int gg = tid & 127;    // gate group -> gates 4gg..4gg+3

    __shared__ __align__(16) float h_s[HID];
    __shared__ __align__(16) float part[4*GATES];   // part[kc*512 + gate]

    // weights: w4[g][k4] = Whh[(4gg+g)*128 + kc*32 + k4*4 ..]
    float4 w4[4][8];
    #pragma unroll
    for (int g = 0; g < 4; g++) {
        const float4* wr = (const float4*)(Whh_l + (size_t)(4*gg + g)*HID + kc*32);
        #pragma unroll
        for (int k = 0; k < 8; k++) w4[g][k] = wr[k];
    }

    float c = 0.f;
    if (tid < HID) h_s[tid] = 0.f;
    __syncthreads();

    const float* xg_b = Xg + (size_t)b*TT*GATES;
    float* hout_b = hseq_l + (size_t)b*TT*HID;

    for (int t = 0; t < TT; t++) {
        // prefetch this step's xg for the reduction threads (latency hides behind matvec)
        float xg4[4];
        if (tid < HID) {
            #pragma unroll
            for (int u = 0; u < 4; u++) xg4[u] = xg_b[t*GATES + u*HID + tid];
        }

        // matvec partials: read own h chunk (broadcast), 128 fma, write 4 partials
        {
            float4 hc[8];
            const float4* h4 = (const float4*)(h_s + kc*32);
            #pragma unroll
            for (int k = 0; k < 8; k++) hc[k] = h4[k];
            float acc[4] = {0.f, 0.f, 0.f, 0.f};
            #pragma unroll
            for (int k = 0; k < 8; k++) {
                float4 hv = hc[k];
                #pragma unroll
                for (int g = 0; g < 4; g++) {
                    acc[g] += w4[g][k].x*hv.x + w4[g][k].y*hv.y
                            + w4[g][k].z*hv.z + w4[g][k].w*hv.w;
                }
            }
            float4 st = {acc[0], acc[1], acc[2], acc[3]};
            *(float4*)(&part[kc*GATES + 4*gg]) = st;
        }
        __syncthreads();

        // reduce + gate math (threads 0..127, j = tid)
        if (tid < HID) {
            float g4[4];
            #pragma unroll
            for (int u = 0; u < 4; u++) {
                float s = xg4[u];
                #pragma unroll
                for (int kcc = 0; kcc < 4; kcc++) s += part[kcc*GATES + u*HID + tid];
                g4[u] = s;
            }
            float si = 1.f/(1.f + __expf(-g4[0]));
            float sf = 1.f/(1.f + __expf(-g4[1]));
            float so = 1.f/(1.f + __expf(-g4[3]));
            float tg = tanhf(g4[2]);
            c = sf*c + si*tg;
            float h = so*tanhf(c);
            h_s[tid] = h;
            hout_b[t*HID + tid] = h;
        }
        __syncthreads();
    }
}

// ---------------- K4: final linear ----------------
__global__ void final_lin(const float* __restrict__ ws, const float* __restrict__ Wlin,
                          const float* __restrict__ blin, float* __restrict__ out) {
    const int b = blockIdx.x, l = threadIdx.x;  // 64 threads
    float acc = 0.f;
    #pragma unroll
    for (int u = 0; u < 8; u++) {
        int idx = u*64 + l;
        int layer = idx >> 7, k = idx & 127;
        const float* hs = ws + WS_HSEQ0 + (size_t)layer*HSEQ_SZ;
        acc += hs[((size_t)b*TT + (TT-1))*HID + k] * Wlin[idx];
    }
    #pragma unroll
    for (int d = 1; d < 64; d <<= 1) acc += __shfl_xor(acc, d);
    if (l == 0) out[b] = acc + blin[0];
}

extern "C" void kernel_launch(void* const* d_in, const int* in_sizes, int n_in,
                              void* d_out, int out_size, void* d_ws, size_t ws_size,
                              hipStream_t stream) {
    const float* x    = (const float*)d_in[0];
    const int*   adj  = (const int*)d_in[1];
    const float* W1   = (const float*)d_in[2];
    const float* a1   = (const float*)d_in[3];
    const float* W2   = (const float*)d_in[4];
    const float* a2   = (const float*)d_in[5];
    const float* Wih  = (const float*)d_in[6];
    const float* Whh  = (const float*)d_in[7];
    const float* bih  = (const float*)d_in[8];
    const float* bhh  = (const float*)d_in[9];
    const float* Wlin = (const float*)d_in[10];
    const float* blin = (const float*)d_in[11];
    const int*   site = (const int*)d_in[12];
    float* ws  = (float*)d_ws;
    float* out = (float*)d_out;

    prep_kernel<<<1, 256, 0, stream>>>(W1, a1, W2, a2, bih, bhh, ws);
    gat_fused<<<dim3(TT, BB), 256, 0, stream>>>(x, adj, W1, ws, ws + WS_SEQ, site);
    for (int l = 0; l < NLAYERS; l++) {
        const float* in_seq = (l == 0) ? (ws + WS_SEQ) : (ws + WS_HSEQ0 + (size_t)(l-1)*HSEQ_SZ);
        lstm_ingemm<<<256, 512, 0, stream>>>(in_seq, Wih + (size_t)l*GATES*HID,
                                             ws + WS_BSUM + l*GATES, ws + WS_XG);
        lstm_rec<<<64, 512, 0, stream>>>(ws + WS_XG, Whh + (size_t)l*GATES*HID,
                                         ws + WS_HSEQ0 + (size_t)l*HSEQ_SZ);
    }
    final_lin<<<64, 64, 0, stream>>>(ws, Wlin, blin, out);
}

// Round 3
// 1126.085 us; speedup vs baseline: 1.5908x; 1.3809x over previous
//
#include <hip/hip_runtime.h>
#include <hip/hip_bf16.h>

// Problem dims
#define BB 64
#define TT 168
#define NN 64
#define FF 17
#define HID 128
#define GATES 512   // 4*HID
#define NLAYERS 4
#define NROWS (BB*TT)   // 10752

// Workspace layout (float offsets)
#define WS_W1SRC 0
#define WS_W1DST 32
#define WS_W2SRC 64
#define WS_W2DST 192
#define WS_BSUM  320                    // 4*512
#define WS_W2T   2560                   // 128*128
#define WS_SEQ   19456                  // NROWS*HID = 1376256
#define WS_XG    1395712                // NROWS*512 = 5505024
#define WS_HSEQ0 6900736                // 4 buffers of NROWS*HID
#define HSEQ_SZ  1376256

// LDS-only barrier: s_waitcnt lgkmcnt(0) + raw s_barrier.
// Avoids __syncthreads' vmcnt(0) drain (which would stall on in-flight
// global stores/prefetch loads every step of the LSTM recurrence).
__device__ __forceinline__ void lds_barrier() {
    __asm__ volatile("" ::: "memory");
    __builtin_amdgcn_s_waitcnt(0xc07f);   // lgkmcnt(0), vmcnt/expcnt untouched
    __builtin_amdgcn_s_barrier();
    __asm__ volatile("" ::: "memory");
}

__device__ __forceinline__ float fsig(float x) {
    return __builtin_amdgcn_rcpf(1.f + __expf(-x));
}
__device__ __forceinline__ float ftanh(float x) {
    // 1 - 2/(e^{2x}+1): monotone, saturates to +-1 without NaN at extremes
    float e = __expf(2.f * x);
    return 1.f - 2.f * __builtin_amdgcn_rcpf(e + 1.f);
}

// ---------------- K0: small precompute ----------------
__global__ void prep_kernel(const float* __restrict__ W1, const float* __restrict__ a1,
                            const float* __restrict__ W2, const float* __restrict__ a2,
                            const float* __restrict__ bih, const float* __restrict__ bhh,
                            float* __restrict__ ws) {
    int tid = threadIdx.x;
    if (tid < 34) {
        int f = tid % FF, half = tid / FF;
        float acc = 0.f;
        for (int o = 0; o < HID; o++) acc += W1[f*HID + o] * a1[half*HID + o];
        ws[(half ? WS_W1DST : WS_W1SRC) + f] = acc;
    }
    {
        int k = tid & 127, half = tid >> 7;
        float acc = 0.f;
        for (int o = 0; o < HID; o++) acc += W2[k*HID + o] * a2[half*HID + o];
        ws[(half ? WS_W2DST : WS_W2SRC) + k] = acc;
    }
    for (int idx = tid; idx < NLAYERS*GATES; idx += 256) ws[WS_BSUM + idx] = bih[idx] + bhh[idx];
    for (int idx = tid; idx < HID*HID; idx += 256) {
        int k = idx >> 7, o = idx & 127;
        ws[WS_W2T + o*HID + k] = W2[idx];
    }
}

// ---------------- K1: fused GAT1 + GAT2(site row), h1 register-resident ----------------
struct __align__(16) GatSmem {
    float attn[64*68];                              // P2 writes, P3 reads (stride 68)
    union { float xsT[FF*64]; float part_d[64*17]; } u1;   // xsT: P0-P3; part_d: P4-P5
    union { float xbarT[FF*64]; float part_h[16*136]; } u2; // xbarT: P3-P4; part_h: P6-P6b
    float src1[64], dst1[64], rinv[64], dst2[64], att2[64];
    float hbar[HID];
    float part_s[16];
    unsigned long long adjbits[64];
};
// ~32.8 KB -> 4 blocks/CU (was 52.5 KB -> 3)

__global__ __launch_bounds__(256) void gat_fused(const float* __restrict__ x, const int* __restrict__ adj,
                                                 const float* __restrict__ W1, const float* __restrict__ ws,
                                                 float* __restrict__ seq, const int* __restrict__ site_ptr) {
    __shared__ GatSmem sm;
    const int tid = threadIdx.x;
    const int tt = blockIdx.x, bb = blockIdx.y;
    const int site = site_ptr[0];
    const float* xblk = x + ((size_t)(bb*TT + tt)) * (NN*FF);

    // P0: x transposed into LDS, adjacency bitmasks
    for (int idx = tid; idx < NN*FF; idx += 256) {
        int n = idx / FF, f = idx % FF;
        sm.u1.xsT[f*64 + n] = xblk[idx];
    }
    {
        int w = tid >> 6, lane = tid & 63;
        for (int r = w*16; r < w*16 + 16; r++) {
            int val = adj[r*64 + lane];
            unsigned long long m = __ballot(val > 0);
            if (lane == 0) sm.adjbits[r] = m | (1ull << r);
        }
    }
    lds_barrier();

    // P1: src1/dst1
    if (tid < 128) {
        int n = tid & 63, half = tid >> 6;
        const float* wv = ws + (half ? WS_W1DST : WS_W1SRC);
        float acc = 0.f;
        #pragma unroll
        for (int f = 0; f < FF; f++) acc += sm.u1.xsT[f*64 + n] * wv[f];
        if (half) sm.dst1[n] = acc; else sm.src1[n] = acc;
    }
    lds_barrier();

    // P2: attention logits -> exp -> attn rows (float4 packed writes)
    {
        int q = tid & 3, i = tid >> 2;
        unsigned long long ab = sm.adjbits[i];
        float si = sm.src1[i];
        float v[16];
        float vmax = -1e30f;
        #pragma unroll
        for (int u = 0; u < 16; u++) {
            int jj = q*16 + u;
            float e = si + sm.dst1[jj];
            float lv = fmaxf(e, 0.2f*e);
            lv = ((ab >> jj) & 1ull) ? lv : -1e9f;
            v[u] = lv;
            vmax = fmaxf(vmax, lv);
        }
        vmax = fmaxf(vmax, __shfl_xor(vmax, 1, 4));
        vmax = fmaxf(vmax, __shfl_xor(vmax, 2, 4));
        float s = 0.f;
        float* arow = &sm.attn[i*68];
        #pragma unroll
        for (int w = 0; w < 4; w++) {
            float4 pv;
            pv.x = __expf(v[w*4+0] - vmax);
            pv.y = __expf(v[w*4+1] - vmax);
            pv.z = __expf(v[w*4+2] - vmax);
            pv.w = __expf(v[w*4+3] - vmax);
            s += (pv.x + pv.y) + (pv.z + pv.w);
            *(float4*)(arow + q*16 + w*4) = pv;
        }
        s += __shfl_xor(s, 1, 4);
        s += __shfl_xor(s, 2, 4);
        if (q == 0) sm.rinv[i] = 1.f / s;
    }
    lds_barrier();

    // P3: xbarT[f][i] = (P @ X)[i][f] * rinv
    {
        int i = tid & 63, q = tid >> 6;
        const float* arow = &sm.attn[i*68];
        float acc[5] = {0.f,0.f,0.f,0.f,0.f};
        const int nf = (q == 0) ? 5 : 4;
        for (int j4 = 0; j4 < 16; j4++) {
            float4 a4 = *(const float4*)(arow + j4*4);
            #pragma unroll
            for (int u = 0; u < 5; u++) {
                if (u < nf) {
                    int f = q + 4*u;
                    float4 x4 = *(const float4*)(&sm.u1.xsT[f*64 + j4*4]);
                    acc[u] += a4.x*x4.x + a4.y*x4.y + a4.z*x4.z + a4.w*x4.w;
                }
            }
        }
        float ri = sm.rinv[i];
        #pragma unroll
        for (int u = 0; u < 5; u++) {
            if (u < nf) sm.u2.xbarT[(q + 4*u)*64 + i] = acc[u] * ri;
        }
    }
    lds_barrier();

    // P4: h1 tile in registers: acc[u][v] = h1[ig*4+u][og*8+v]; also dst2/src2 partials
    const int og = tid & 15, ig = tid >> 4;
    float acc[4][8];
    {
        #pragma unroll
        for (int u = 0; u < 4; u++)
            #pragma unroll
            for (int v = 0; v < 8; v++) acc[u][v] = 0.f;
        #pragma unroll
        for (int f = 0; f < FF; f++) {
            float4 xb = *(const float4*)(&sm.u2.xbarT[f*64 + ig*4]);
            float4 wa = *(const float4*)(W1 + f*HID + og*8);
            float4 wb = *(const float4*)(W1 + f*HID + og*8 + 4);
            float xv[4] = {xb.x, xb.y, xb.z, xb.w};
            float wv[8] = {wa.x, wa.y, wa.z, wa.w, wb.x, wb.y, wb.z, wb.w};
            #pragma unroll
            for (int u = 0; u < 4; u++)
                #pragma unroll
                for (int v = 0; v < 8; v++) acc[u][v] += xv[u] * wv[v];
        }
        // dst2 partials (and src2 partials for the site row)
        float4 da = *(const float4*)(ws + WS_W2DST + og*8);
        float4 db = *(const float4*)(ws + WS_W2DST + og*8 + 4);
        float4 sa = *(const float4*)(ws + WS_W2SRC + og*8);
        float4 sb = *(const float4*)(ws + WS_W2SRC + og*8 + 4);
        float dv[8] = {da.x, da.y, da.z, da.w, db.x, db.y, db.z, db.w};
        float sv[8] = {sa.x, sa.y, sa.z, sa.w, sb.x, sb.y, sb.z, sb.w};
        #pragma unroll
        for (int u = 0; u < 4; u++) {
            float pd = 0.f, ps = 0.f;
            #pragma unroll
            for (int v = 0; v < 8; v++) { pd += acc[u][v]*dv[v]; ps += acc[u][v]*sv[v]; }
            sm.u1.part_d[(ig*4+u)*17 + og] = pd;
            if (ig*4 + u == site) sm.part_s[og] = ps;
        }
    }
    lds_barrier();

    // P5 (wave 0 only): reduce dst2 + src2, masked softmax over site row -> att2
    if (tid < 64) {
        int jj = tid;
        float d = 0.f;
        #pragma unroll
        for (int o = 0; o < 16; o++) d += sm.u1.part_d[jj*17 + o];
        float sp = sm.part_s[tid & 15];
        sp += __shfl_xor(sp, 1);
        sp += __shfl_xor(sp, 2);
        sp += __shfl_xor(sp, 4);
        sp += __shfl_xor(sp, 8);        // every lane: full sum over 16 partials
        unsigned long long ab = sm.adjbits[site];
        float e = sp + d;
        float lv = fmaxf(e, 0.2f*e);
        lv = ((ab >> jj) & 1ull) ? lv : -1e9f;
        float m = lv;
        #pragma unroll
        for (int dd = 1; dd < 64; dd <<= 1) m = fmaxf(m, __shfl_xor(m, dd));
        float p = __expf(lv - m);
        float s = p;
        #pragma unroll
        for (int dd = 1; dd < 64; dd <<= 1) s += __shfl_xor(s, dd);
        sm.att2[jj] = p / s;
    }
    lds_barrier();

    // P6: hbar partials from register-resident h1
    {
        float hp[8];
        #pragma unroll
        for (int v = 0; v < 8; v++) hp[v] = 0.f;
        #pragma unroll
        for (int u = 0; u < 4; u++) {
            float a = sm.att2[ig*4 + u];
            #pragma unroll
            for (int v = 0; v < 8; v++) hp[v] += a * acc[u][v];
        }
        float4 h0 = {hp[0], hp[1], hp[2], hp[3]};
        float4 h1v = {hp[4], hp[5], hp[6], hp[7]};
        *(float4*)(&sm.u2.part_h[ig*136 + og*8])     = h0;
        *(float4*)(&sm.u2.part_h[ig*136 + og*8 + 4]) = h1v;
    }
    lds_barrier();

    // P6b: reduce hbar over ig
    if (tid < 128) {
        float s = 0.f;
        #pragma unroll
        for (int g = 0; g < 16; g++) s += sm.u2.part_h[g*136 + tid];
        sm.hbar[tid] = s;
    }
    lds_barrier();

    // P7: seq[b][t][o] = hbar @ W2
    if (tid < 128) {
        int o = tid;
        const float4* w2t = (const float4*)(ws + WS_W2T + o*HID);
        const float4* hb4 = (const float4*)sm.hbar;
        float a = 0.f;
        #pragma unroll
        for (int k4 = 0; k4 < 32; k4++) {
            float4 h4 = hb4[k4], w4 = w2t[k4];
            a += h4.x*w4.x + h4.y*w4.y + h4.z*w4.z + h4.w*w4.w;
        }
        seq[((size_t)(bb*TT + tt))*HID + o] = a;
    }
}

// ---------------- K2: input GEMM  Xg[r][j] = seq[r] . Wih[j] + bsum[j] ----------------
// grid 672 x 16 rows, 2-row ILP pairing
__global__ __launch_bounds__(512, 2) void lstm_ingemm(const float* __restrict__ in_seq,
                                                      const float* __restrict__ Wih_l,
                                                      const float* __restrict__ bsum_l,
                                                      float* __restrict__ Xg) {
    const int j = threadIdx.x;
    const float4* wr = (const float4*)(Wih_l + j*HID);
    float4 w[32];
    #pragma unroll
    for (int k = 0; k < 32; k++) w[k] = wr[k];
    const float bj = bsum_l[j];
    const int r0 = blockIdx.x * 16;
    for (int rr = 0; rr < 16; rr += 2) {
        int r = r0 + rr;
        const float4* x0 = (const float4*)(in_seq + (size_t)r*HID);
        const float4* x1 = x0 + 32;
        float a0x=0.f,a0y=0.f,a0z=0.f,a0w=0.f;
        float a1x=0.f,a1y=0.f,a1z=0.f,a1w=0.f;
        #pragma unroll
        for (int k = 0; k < 32; k++) {
            float4 v0 = x0[k];
            float4 v1 = x1[k];
            a0x += w[k].x*v0.x; a0y += w[k].y*v0.y; a0z += w[k].z*v0.z; a0w += w[k].w*v0.w;
            a1x += w[k].x*v1.x; a1y += w[k].y*v1.y; a1z += w[k].z*v1.z; a1w += w[k].w*v1.w;
        }
        Xg[(size_t)r*GATES + j]     = bj + ((a0x+a0y)+(a0z+a0w));
        Xg[(size_t)(r+1)*GATES + j] = bj + ((a1x+a1y)+(a1z+a1w));
    }
}

// ---------------- K3: recurrence, one block per batch element ----------------
// Outer-product tiling (thread = 4 gates x 32-k-chunk) + LDS-only barriers
// + 1-step register prefetch of Xg + fast exp-based gates.
__global__ __launch_bounds__(512, 2) void lstm_rec(const float* __restrict__ Xg,
                                                   const float* __restrict__ Whh_l,
                                                   float* __restrict__ hseq_l) {
    const int b = blockIdx.x;
    const int tid = threadIdx.x;
    const int kc = tid >> 7;     // wave-uniform -> h reads broadcast
    const int gg = tid & 127;

    __shared__ __align__(16) float h_s[HID];
    __shared__ __align__(16) float part[4*GATES];

    float4 w4[4][8];
    #pragma unroll
    for (int g = 0; g < 4; g++) {
        const float4* wr = (const float4*)(Whh_l + (size_t)(4*gg + g)*HID + kc*32);
        #pragma unroll
        for (int k = 0; k < 8; k++) w4[g][k] = wr[k];
    }

    float c = 0.f;
    if (tid < HID) h_s[tid] = 0.f;

    const float* xg_b = Xg + (size_t)b*TT*GATES;
    float* hout_b = hseq_l + (size_t)b*TT*HID;

    float xgc[4], xgn[4];
    if (tid < HID) {
        #pragma unroll
        for (int u = 0; u < 4; u++) xgc[u] = xg_b[u*HID + tid];
    }
    lds_barrier();

    for (int t = 0; t < TT; t++) {
        // prefetch next step's xg (in flight across both raw barriers)
        if (tid < HID && t + 1 < TT) {
            const float* p = xg_b + (size_t)(t+1)*GATES + tid;
            #pragma unroll
            for (int u = 0; u < 4; u++) xgn[u] = p[u*HID];
        }

        // matvec partials
        {
            float4 hc[8];
            const float4* h4 = (const float4*)(h_s + kc*32);
            #pragma unroll
            for (int k = 0; k < 8; k++) hc[k] = h4[k];
            float a[4] = {0.f, 0.f, 0.f, 0.f};
            #pragma unroll
            for (int k = 0; k < 8; k++) {
                float4 hv = hc[k];
                #pragma unroll
                for (int g = 0; g < 4; g++) {
                    a[g] += w4[g][k].x*hv.x + w4[g][k].y*hv.y
                          + w4[g][k].z*hv.z + w4[g][k].w*hv.w;
                }
            }
            float4 st = {a[0], a[1], a[2], a[3]};
            *(float4*)(&part[kc*GATES + 4*gg]) = st;
        }
        lds_barrier();

        // reduce + gate math
        if (tid < HID) {
            float g4[4];
            #pragma unroll
            for (int u = 0; u < 4; u++) {
                float s = xgc[u];
                #pragma unroll
                for (int kcc = 0; kcc < 4; kcc++) s += part[kcc*GATES + u*HID + tid];
                g4[u] = s;
            }
            float si = fsig(g4[0]);
            float sf = fsig(g4[1]);
            float so = fsig(g4[3]);
            float tg = ftanh(g4[2]);
            c = sf*c + si*tg;
            float h = so*ftanh(c);
            h_s[tid] = h;
            hout_b[t*HID + tid] = h;    // fire-and-forget (no vmcnt drain at barriers)
        }
        lds_barrier();

        if (tid < HID) {
            #pragma unroll
            for (int u = 0; u < 4; u++) xgc[u] = xgn[u];
        }
    }
}

// ---------------- K4: final linear ----------------
__global__ void final_lin(const float* __restrict__ ws, const float* __restrict__ Wlin,
                          const float* __restrict__ blin, float* __restrict__ out) {
    const int b = blockIdx.x, l = threadIdx.x;  // 64 threads
    float acc = 0.f;
    #pragma unroll
    for (int u = 0; u < 8; u++) {
        int idx = u*64 + l;
        int layer = idx >> 7, k = idx & 127;
        const float* hs = ws + WS_HSEQ0 + (size_t)layer*HSEQ_SZ;
        acc += hs[((size_t)b*TT + (TT-1))*HID + k] * Wlin[idx];
    }
    #pragma unroll
    for (int d = 1; d < 64; d <<= 1) acc += __shfl_xor(acc, d);
    if (l == 0) out[b] = acc + blin[0];
}

extern "C" void kernel_launch(void* const* d_in, const int* in_sizes, int n_in,
                              void* d_out, int out_size, void* d_ws, size_t ws_size,
                              hipStream_t stream) {
    const float* x    = (const float*)d_in[0];
    const int*   adj  = (const int*)d_in[1];
    const float* W1   = (const float*)d_in[2];
    const float* a1   = (const float*)d_in[3];
    const float* W2   = (const float*)d_in[4];
    const float* a2   = (const float*)d_in[5];
    const float* Wih  = (const float*)d_in[6];
    const float* Whh  = (const float*)d_in[7];
    const float* bih  = (const float*)d_in[8];
    const float* bhh  = (const float*)d_in[9];
    const float* Wlin = (const float*)d_in[10];
    const float* blin = (const float*)d_in[11];
    const int*   site = (const int*)d_in[12];
    float* ws  = (float*)d_ws;
    float* out = (float*)d_out;

    prep_kernel<<<1, 256, 0, stream>>>(W1, a1, W2, a2, bih, bhh, ws);
    gat_fused<<<dim3(TT, BB), 256, 0, stream>>>(x, adj, W1, ws, ws + WS_SEQ, site);
    for (int l = 0; l < NLAYERS; l++) {
        const float* in_seq = (l == 0) ? (ws + WS_SEQ) : (ws + WS_HSEQ0 + (size_t)(l-1)*HSEQ_SZ);
        lstm_ingemm<<<NROWS/16, 512, 0, stream>>>(in_seq, Wih + (size_t)l*GATES*HID,
                                                  ws + WS_BSUM + l*GATES, ws + WS_XG);
        lstm_rec<<<64, 512, 0, stream>>>(ws + WS_XG, Whh + (size_t)l*GATES*HID,
                                         ws + WS_HSEQ0 + (size_t)l*HSEQ_SZ);
    }
    final_lin<<<64, 64, 0, stream>>>(ws, Wlin, blin, out);
}

// Round 4
// 962.556 us; speedup vs baseline: 1.8610x; 1.1699x over previous
//
#include <hip/hip_runtime.h>
#include <hip/hip_bf16.h>

// Problem dims
#define BB 64
#define TT 168
#define NN 64
#define FF 17
#define HID 128
#define GATES 512   // 4*HID
#define NLAYERS 4
#define NROWS (BB*TT)   // 10752

// Workspace layout (float offsets)
#define WS_W1SRC 0
#define WS_W1DST 32
#define WS_W2SRC 64
#define WS_W2DST 192
#define WS_BSUM  320                    // 4*512 -> ends 2368
#define WS_WD    2560                   // 17 (pad 32): W1 @ (W2 @ a2dst)
#define WS_WSV   2592                   // 17 (pad 32): W1 @ (W2 @ a2src)
#define WS_W12   2624                   // 17*128 = 2176: W1 @ W2
#define WS_WXG0T 4800                   // 512*20 (17 used): (W12 @ Wih0^T)^T rows
#define WS_XG    1395712                // NROWS*512 = 5505024
#define WS_HSEQ0 6900736                // 4 buffers of NROWS*HID
#define HSEQ_SZ  1376256

// LDS-only barrier: s_waitcnt lgkmcnt(0) + raw s_barrier (no vmcnt drain).
__device__ __forceinline__ void lds_barrier() {
    __asm__ volatile("" ::: "memory");
    __builtin_amdgcn_s_waitcnt(0xc07f);
    __builtin_amdgcn_s_barrier();
    __asm__ volatile("" ::: "memory");
}

__device__ __forceinline__ float fsig(float x) {
    return __builtin_amdgcn_rcpf(1.f + __expf(-x));
}
__device__ __forceinline__ float ftanh(float x) {
    float e = __expf(2.f * x);
    return 1.f - 2.f * __builtin_amdgcn_rcpf(e + 1.f);
}
__device__ __forceinline__ float bcast_lane(float v, int lane) {
    return __int_as_float(__builtin_amdgcn_readlane(__float_as_int(v), lane));
}

// ---------------- prep1: attention projection vectors + bias sums ----------------
__global__ void prep1(const float* __restrict__ W1, const float* __restrict__ a1,
                      const float* __restrict__ W2, const float* __restrict__ a2,
                      const float* __restrict__ bih, const float* __restrict__ bhh,
                      float* __restrict__ ws) {
    int tid = threadIdx.x;
    if (tid < 34) {
        int f = tid % FF, half = tid / FF;
        float acc = 0.f;
        for (int o = 0; o < HID; o++) acc += W1[f*HID + o] * a1[half*HID + o];
        ws[(half ? WS_W1DST : WS_W1SRC) + f] = acc;
    }
    {
        int k = tid & 127, half = tid >> 7;
        float acc = 0.f;
        for (int o = 0; o < HID; o++) acc += W2[k*HID + o] * a2[half*HID + o];
        ws[(half ? WS_W2DST : WS_W2SRC) + k] = acc;
    }
    for (int idx = tid; idx < NLAYERS*GATES; idx += 256) ws[WS_BSUM + idx] = bih[idx] + bhh[idx];
}

// ---------------- prep2: W12 = W1 @ W2 (17 x 128) ----------------
__global__ void prep2(const float* __restrict__ W1, const float* __restrict__ W2,
                      float* __restrict__ ws) {
    int f = blockIdx.x, o = threadIdx.x;
    float acc = 0.f;
    for (int k = 0; k < HID; k++) acc += W1[f*HID + k] * W2[k*HID + o];
    ws[WS_W12 + f*HID + o] = acc;
}

// ---------------- prep3: WD/WSV (17 each) + WXG0T (512 x 17, stride 20) ----------------
__global__ void prep3(const float* __restrict__ W1, const float* __restrict__ Wih0,
                      float* __restrict__ ws) {
    int idx = blockIdx.x * 256 + threadIdx.x;
    if (idx < 17) {
        int f = idx;
        float acc = 0.f;
        for (int k = 0; k < HID; k++) acc += W1[f*HID + k] * ws[WS_W2DST + k];
        ws[WS_WD + f] = acc;
    } else if (idx < 34) {
        int f = idx - 17;
        float acc = 0.f;
        for (int k = 0; k < HID; k++) acc += W1[f*HID + k] * ws[WS_W2SRC + k];
        ws[WS_WSV + f] = acc;
    } else if (idx < 34 + GATES*FF) {
        int e = idx - 34;
        int j = e % GATES, f = e / GATES;   // f < 17
        float acc = 0.f;
        for (int o = 0; o < HID; o++) acc += ws[WS_W12 + f*HID + o] * Wih0[j*HID + o];
        ws[WS_WXG0T + j*20 + f] = acc;
    }
}

// ---------------- K1: fused GAT1 + GAT2(site) -> Xg layer-0 directly ----------------
// h1 never materialized: all GAT2 quantities are linear in xbar = attn1 @ x (width 17).
struct __align__(16) GatSmem {
    float attn[64*68];       // P2 writes rows (stride 68), P3 reads
    float xsT[FF*64];        // [f][n]
    float xbarT[FF*68];      // [f][i], stride 68
    float src1[64], dst1[64], rinv[64], att2[64];
    float xbar2[20];
    float part_x[FF*8];      // P5a partials
    unsigned long long adjbits[64];
};
// ~28.5 KB -> 5 blocks/CU

__global__ __launch_bounds__(256) void gat_fused(const float* __restrict__ x, const int* __restrict__ adj,
                                                 const float* __restrict__ ws,
                                                 float* __restrict__ Xg, const int* __restrict__ site_ptr) {
    __shared__ GatSmem sm;
    const int tid = threadIdx.x;
    const int tt = blockIdx.x, bb = blockIdx.y;
    const int site = site_ptr[0];
    const int r = bb*TT + tt;
    const float* xblk = x + (size_t)r * (NN*FF);

    // P0: x transposed into LDS, adjacency bitmasks
    for (int idx = tid; idx < NN*FF; idx += 256) {
        int n = idx / FF, f = idx % FF;
        sm.xsT[f*64 + n] = xblk[idx];
    }
    {
        int w = tid >> 6, lane = tid & 63;
        for (int rr = w*16; rr < w*16 + 16; rr++) {
            int val = adj[rr*64 + lane];
            unsigned long long m = __ballot(val > 0);
            if (lane == 0) sm.adjbits[rr] = m | (1ull << rr);
        }
    }
    lds_barrier();

    // P1: src1/dst1 = x . (W1 @ a1-halves)
    if (tid < 128) {
        int n = tid & 63, half = tid >> 6;
        const float* wv = ws + (half ? WS_W1DST : WS_W1SRC);
        float acc = 0.f;
        #pragma unroll
        for (int f = 0; f < FF; f++) acc += sm.xsT[f*64 + n] * wv[f];
        if (half) sm.dst1[n] = acc; else sm.src1[n] = acc;
    }
    lds_barrier();

    // P2: attention logits -> exp -> attn rows
    {
        int q = tid & 3, i = tid >> 2;
        unsigned long long ab = sm.adjbits[i];
        float si = sm.src1[i];
        float v[16];
        float vmax = -1e30f;
        #pragma unroll
        for (int u = 0; u < 16; u++) {
            int jj = q*16 + u;
            float e = si + sm.dst1[jj];
            float lv = fmaxf(e, 0.2f*e);
            lv = ((ab >> jj) & 1ull) ? lv : -1e9f;
            v[u] = lv;
            vmax = fmaxf(vmax, lv);
        }
        vmax = fmaxf(vmax, __shfl_xor(vmax, 1, 4));
        vmax = fmaxf(vmax, __shfl_xor(vmax, 2, 4));
        float s = 0.f;
        float* arow = &sm.attn[i*68];
        #pragma unroll
        for (int w = 0; w < 4; w++) {
            float4 pv;
            pv.x = __expf(v[w*4+0] - vmax);
            pv.y = __expf(v[w*4+1] - vmax);
            pv.z = __expf(v[w*4+2] - vmax);
            pv.w = __expf(v[w*4+3] - vmax);
            s += (pv.x + pv.y) + (pv.z + pv.w);
            *(float4*)(arow + q*16 + w*4) = pv;
        }
        s += __shfl_xor(s, 1, 4);
        s += __shfl_xor(s, 2, 4);
        if (q == 0) sm.rinv[i] = 1.f / s;
    }
    lds_barrier();

    // P3: xbarT[f][i] = (P @ X)[i][f] * rinv  (the only real GEMM left)
    {
        int i = tid & 63, q = tid >> 6;
        const float* arow = &sm.attn[i*68];
        float acc[5] = {0.f,0.f,0.f,0.f,0.f};
        const int nf = (q == 0) ? 5 : 4;
        for (int j4 = 0; j4 < 16; j4++) {
            float4 a4 = *(const float4*)(arow + j4*4);
            #pragma unroll
            for (int u = 0; u < 5; u++) {
                if (u < nf) {
                    int f = q + 4*u;
                    float4 x4 = *(const float4*)(&sm.xsT[f*64 + j4*4]);
                    acc[u] += a4.x*x4.x + a4.y*x4.y + a4.z*x4.z + a4.w*x4.w;
                }
            }
        }
        float ri = sm.rinv[i];
        #pragma unroll
        for (int u = 0; u < 5; u++) {
            if (u < nf) sm.xbarT[(q + 4*u)*68 + i] = acc[u] * ri;
        }
    }
    lds_barrier();

    // P4' (wave 0): dst2[j] = xbar[j].WD ; src2 = xbar[site].WSV ; softmax -> att2
    if (tid < 64) {
        int jj = tid;
        float d = 0.f, sp = 0.f;
        #pragma unroll
        for (int f = 0; f < FF; f++) {
            float xv = sm.xbarT[f*68 + jj];
            float xs = sm.xbarT[f*68 + site];   // broadcast
            d  += xv * ws[WS_WD + f];           // wave-uniform -> s_load
            sp += xs * ws[WS_WSV + f];
        }
        unsigned long long ab = sm.adjbits[site];
        float e = sp + d;
        float lv = fmaxf(e, 0.2f*e);
        lv = ((ab >> jj) & 1ull) ? lv : -1e9f;
        float m = lv;
        #pragma unroll
        for (int dd = 1; dd < 64; dd <<= 1) m = fmaxf(m, __shfl_xor(m, dd));
        float p = __expf(lv - m);
        float s = p;
        #pragma unroll
        for (int dd = 1; dd < 64; dd <<= 1) s += __shfl_xor(s, dd);
        sm.att2[jj] = p / s;
    }
    lds_barrier();

    // P5a: xbar2 partials: thread (f, c) sums 8 nodes
    if (tid < FF*8) {
        int f = tid >> 3, c = tid & 7;
        float p = 0.f;
        #pragma unroll
        for (int u = 0; u < 8; u++) {
            int i = c*8 + u;
            p += sm.att2[i] * sm.xbarT[f*68 + i];
        }
        sm.part_x[f*8 + c] = p;
    }
    lds_barrier();

    // P5b: reduce xbar2
    if (tid < FF) {
        float s = 0.f;
        #pragma unroll
        for (int c = 0; c < 8; c++) s += sm.part_x[tid*8 + c];
        sm.xbar2[tid] = s;
    }
    lds_barrier();

    // P6': Xg0[r][j] = xbar2 . WXG0T[j] + bsum0[j]   (2 gates per thread)
    {
        float xb[FF];
        #pragma unroll
        for (int f = 0; f < FF; f++) xb[f] = sm.xbar2[f];
        #pragma unroll
        for (int half = 0; half < 2; half++) {
            int j = tid + half*256;
            const float4* wp = (const float4*)(ws + WS_WXG0T + j*20);
            float4 w0 = wp[0], w1 = wp[1], w2 = wp[2], w3 = wp[3];
            float wlast = ws[WS_WXG0T + j*20 + 16];
            float acc = ws[WS_BSUM + j];
            acc += w0.x*xb[0] + w0.y*xb[1] + w0.z*xb[2] + w0.w*xb[3];
            acc += w1.x*xb[4] + w1.y*xb[5] + w1.z*xb[6] + w1.w*xb[7];
            acc += w2.x*xb[8] + w2.y*xb[9] + w2.z*xb[10] + w2.w*xb[11];
            acc += w3.x*xb[12] + w3.y*xb[13] + w3.z*xb[14] + w3.w*xb[15];
            acc += wlast*xb[16];
            Xg[(size_t)r*GATES + j] = acc;
        }
    }
}

// ---------------- K2: input GEMM  Xg[r][j] = seq[r] . Wih[j] + bsum[j] (layers 1-3) ----------------
__global__ __launch_bounds__(512, 2) void lstm_ingemm(const float* __restrict__ in_seq,
                                                      const float* __restrict__ Wih_l,
                                                      const float* __restrict__ bsum_l,
                                                      float* __restrict__ Xg) {
    const int j = threadIdx.x;
    const float4* wr = (const float4*)(Wih_l + j*HID);
    float4 w[32];
    #pragma unroll
    for (int k = 0; k < 32; k++) w[k] = wr[k];
    const float bj = bsum_l[j];
    const int r0 = blockIdx.x * 16;
    for (int rr = 0; rr < 16; rr += 2) {
        int r = r0 + rr;
        const float4* x0 = (const float4*)(in_seq + (size_t)r*HID);
        const float4* x1 = x0 + 32;
        float a0x=0.f,a0y=0.f,a0z=0.f,a0w=0.f;
        float a1x=0.f,a1y=0.f,a1z=0.f,a1w=0.f;
        #pragma unroll
        for (int k = 0; k < 32; k++) {
            float4 v0 = x0[k];
            float4 v1 = x1[k];
            a0x += w[k].x*v0.x; a0y += w[k].y*v0.y; a0z += w[k].z*v0.z; a0w += w[k].w*v0.w;
            a1x += w[k].x*v1.x; a1y += w[k].y*v1.y; a1z += w[k].z*v1.z; a1w += w[k].w*v1.w;
        }
        Xg[(size_t)r*GATES + j]     = bj + ((a0x+a0y)+(a0z+a0w));
        Xg[(size_t)(r+1)*GATES + j] = bj + ((a1x+a1y)+(a1z+a1w));
    }
}

// ---------------- K3: recurrence ----------------
// h distribution via v_readlane SGPR broadcast: per wave 2 ds_read_b32 (co-op h read)
// instead of 8 ds_read_b128 per thread. LDS pipe /2.5; VALU absorbs 32 readlanes.
__global__ __launch_bounds__(512, 2) void lstm_rec(const float* __restrict__ Xg,
                                                   const float* __restrict__ Whh_l,
                                                   float* __restrict__ hseq_l) {
    const int b = blockIdx.x;
    const int tid = threadIdx.x;
    const int kc = tid >> 7;     // wave-uniform k-chunk
    const int gg = tid & 127;
    const int lane = tid & 63;

    __shared__ __align__(16) float h_s[HID];
    __shared__ __align__(16) float part[4*GATES];

    float w[4][32];
    #pragma unroll
    for (int g = 0; g < 4; g++) {
        const float4* wr = (const float4*)(Whh_l + (size_t)(4*gg + g)*HID + kc*32);
        #pragma unroll
        for (int k4 = 0; k4 < 8; k4++) {
            float4 v = wr[k4];
            w[g][k4*4+0] = v.x; w[g][k4*4+1] = v.y; w[g][k4*4+2] = v.z; w[g][k4*4+3] = v.w;
        }
    }

    const int useB = (kc & 2);
    const int base = __builtin_amdgcn_readfirstlane((kc & 1) << 5);

    float c = 0.f;
    if (tid < HID) h_s[tid] = 0.f;

    const float* xg_b = Xg + (size_t)b*TT*GATES;
    float* hout_b = hseq_l + (size_t)b*TT*HID;

    float xgc[4], xgn[4];
    if (tid < HID) {
        #pragma unroll
        for (int u = 0; u < 4; u++) xgc[u] = xg_b[u*HID + tid];
    }
    lds_barrier();

    for (int t = 0; t < TT; t++) {
        if (tid < HID && t + 1 < TT) {
            const float* p = xg_b + (size_t)(t+1)*GATES + tid;
            #pragma unroll
            for (int u = 0; u < 4; u++) xgn[u] = p[u*HID];
        }

        // co-op h read + readlane broadcast matvec
        {
            float hA = h_s[lane];
            float hB = h_s[64 + lane];
            float hsel = useB ? hB : hA;
            float a0 = 0.f, a1 = 0.f, a2 = 0.f, a3 = 0.f;
            #pragma unroll
            for (int k = 0; k < 32; k++) {
                float hv = bcast_lane(hsel, base + k);
                a0 += w[0][k]*hv; a1 += w[1][k]*hv; a2 += w[2][k]*hv; a3 += w[3][k]*hv;
            }
            float4 st = {a0, a1, a2, a3};
            *(float4*)(&part[kc*GATES + 4*gg]) = st;
        }
        lds_barrier();

        if (tid < HID) {
            float g4[4];
            #pragma unroll
            for (int u = 0; u < 4; u++) {
                float s = xgc[u];
                #pragma unroll
                for (int kcc = 0; kcc < 4; kcc++) s += part[kcc*GATES + u*HID + tid];
                g4[u] = s;
            }
            float si = fsig(g4[0]);
            float sf = fsig(g4[1]);
            float so = fsig(g4[3]);
            float tg = ftanh(g4[2]);
            c = sf*c + si*tg;
            float h = so*ftanh(c);
            h_s[tid] = h;
            hout_b[t*HID + tid] = h;    // fire-and-forget
        }
        lds_barrier();

        if (tid < HID) {
            #pragma unroll
            for (int u = 0; u < 4; u++) xgc[u] = xgn[u];
        }
    }
}

// ---------------- K4: final linear ----------------
__global__ void final_lin(const float* __restrict__ ws, const float* __restrict__ Wlin,
                          const float* __restrict__ blin, float* __restrict__ out) {
    const int b = blockIdx.x, l = threadIdx.x;  // 64 threads
    float acc = 0.f;
    #pragma unroll
    for (int u = 0; u < 8; u++) {
        int idx = u*64 + l;
        int layer = idx >> 7, k = idx & 127;
        const float* hs = ws + WS_HSEQ0 + (size_t)layer*HSEQ_SZ;
        acc += hs[((size_t)b*TT + (TT-1))*HID + k] * Wlin[idx];
    }
    #pragma unroll
    for (int d = 1; d < 64; d <<= 1) acc += __shfl_xor(acc, d);
    if (l == 0) out[b] = acc + blin[0];
}

extern "C" void kernel_launch(void* const* d_in, const int* in_sizes, int n_in,
                              void* d_out, int out_size, void* d_ws, size_t ws_size,
                              hipStream_t stream) {
    const float* x    = (const float*)d_in[0];
    const int*   adj  = (const int*)d_in[1];
    const float* W1   = (const float*)d_in[2];
    const float* a1   = (const float*)d_in[3];
    const float* W2   = (const float*)d_in[4];
    const float* a2   = (const float*)d_in[5];
    const float* Wih  = (const float*)d_in[6];
    const float* Whh  = (const float*)d_in[7];
    const float* bih  = (const float*)d_in[8];
    const float* bhh  = (const float*)d_in[9];
    const float* Wlin = (const float*)d_in[10];
    const float* blin = (const float*)d_in[11];
    const int*   site = (const int*)d_in[12];
    float* ws  = (float*)d_ws;
    float* out = (float*)d_out;

    prep1<<<1, 256, 0, stream>>>(W1, a1, W2, a2, bih, bhh, ws);
    prep2<<<FF, 128, 0, stream>>>(W1, W2, ws);
    prep3<<<35, 256, 0, stream>>>(W1, Wih, ws);
    gat_fused<<<dim3(TT, BB), 256, 0, stream>>>(x, adj, ws, ws + WS_XG, site);
    for (int l = 0; l < NLAYERS; l++) {
        if (l > 0) {
            lstm_ingemm<<<NROWS/16, 512, 0, stream>>>(ws + WS_HSEQ0 + (size_t)(l-1)*HSEQ_SZ,
                                                      Wih + (size_t)l*GATES*HID,
                                                      ws + WS_BSUM + l*GATES, ws + WS_XG);
        }
        lstm_rec<<<64, 512, 0, stream>>>(ws + WS_XG, Whh + (size_t)l*GATES*HID,
                                         ws + WS_HSEQ0 + (size_t)l*HSEQ_SZ);
    }
    final_lin<<<64, 64, 0, stream>>>(ws, Wlin, blin, out);
}